// Round 14
// baseline (415.433 us; speedup 1.0000x reference)
//
#include <hip/hip_runtime.h>

typedef unsigned short USH;
typedef __bf16 v8bf __attribute__((ext_vector_type(8)));
typedef float v4f __attribute__((ext_vector_type(4)));
typedef unsigned short us8 __attribute__((ext_vector_type(8)));

#define SB 2048
#define DD 2048
#define NH 16
#define DPH 128

__device__ __forceinline__ USH f2bf(float f) {
  unsigned u = __float_as_uint(f);
  u = u + 0x7fffu + ((u >> 16) & 1u);
  return (USH)(u >> 16);
}

#define GL16(gp, lp)                                                   \
  __builtin_amdgcn_global_load_lds(                                    \
      (const __attribute__((address_space(1))) void*)(gp),             \
      (__attribute__((address_space(3))) void*)(lp), 16, 0, 0)

// ---- fused prep: [0,4096) x->bf16 | [4096,6144) transpose wq/wk |
//      [6144,8193) wvo | 8193: zero out ----
__global__ __launch_bounds__(256) void k_prep(const float* __restrict__ x,
    const float* __restrict__ wq, const float* __restrict__ wk,
    const float* __restrict__ wvf, const float* __restrict__ bvf,
    const float* __restrict__ wo,
    USH* __restrict__ xb, USH* __restrict__ wqt, USH* __restrict__ wkt,
    USH* __restrict__ wvoT, float* __restrict__ bvo, float* __restrict__ out) {
  __shared__ USH tl[64][72];
  __shared__ float red[256];
  const int bid = blockIdx.x;
  const int t = threadIdx.x;
  if (bid < 4096) {
    const int i = (bid * 256 + t) * 8;
    const float4 a = *(const float4*)&x[i];
    const float4 b = *(const float4*)&x[i + 4];
    v8bf o;
    o[0] = (__bf16)a.x; o[1] = (__bf16)a.y; o[2] = (__bf16)a.z; o[3] = (__bf16)a.w;
    o[4] = (__bf16)b.x; o[5] = (__bf16)b.y; o[6] = (__bf16)b.z; o[7] = (__bf16)b.w;
    *(v8bf*)&xb[i] = o;
  } else if (bid < 6144) {
    const int rel = bid - 4096;
    const int z = rel >> 10, rem = rel & 1023;
    const float* w = z ? wk : wq;
    USH* wt = z ? wkt : wqt;
    const int k0 = (rem >> 5) * 64, j0 = (rem & 31) * 64;
#pragma unroll
    for (int p = 0; p < 4; ++p) {
      const int r = p * 16 + (t >> 4);
      const int c = (t & 15) * 4;
      const float4 v = *(const float4*)&w[(size_t)(k0 + r) * DD + j0 + c];
      tl[c + 0][r] = f2bf(v.x);
      tl[c + 1][r] = f2bf(v.y);
      tl[c + 2][r] = f2bf(v.z);
      tl[c + 3][r] = f2bf(v.w);
    }
    __syncthreads();
#pragma unroll
    for (int p = 0; p < 2; ++p) {
      const int j = p * 32 + (t >> 3);
      const int seg = (t & 7) * 8;
      us8 v = *(const us8*)&tl[j][seg];
      *(us8*)&wt[(size_t)(j0 + j) * DD + k0 + seg] = v;
    }
  } else if (bid < 8193) {
    const int d = bid - 6144;
    const float* src = (d == DD) ? bvf : (wvf + (size_t)d * DD);
    const float4 a0 = *(const float4*)&src[t * 8];
    const float4 a1 = *(const float4*)&src[t * 8 + 4];
    const float4 w0 = *(const float4*)&wo[t * 8];
    const float4 w1 = *(const float4*)&wo[t * 8 + 4];
    red[t] = a0.x * w0.x + a0.y * w0.y + a0.z * w0.z + a0.w * w0.w +
             a1.x * w1.x + a1.y * w1.y + a1.z * w1.z + a1.w * w1.w;
    __syncthreads();
    for (int s = 8; s > 0; s >>= 1) {
      if ((t & 15) < s) red[t] += red[t + s];
      __syncthreads();
    }
    if ((t & 15) == 0) {
      if (d == DD) bvo[t >> 4] = red[t];
      else wvoT[(size_t)(t >> 4) * DD + d] = f2bf(red[t]);
    }
  } else {
    // zero out[4096] for attn's atomicAdd
#pragma unroll
    for (int i = 0; i < 16; ++i) out[i * 256 + t] = 0.f;
  }
}

// ---- 256x256-tile GEMM (waves 0-7) + fused vw (wave 8), 2 barriers/tile ----
__global__ __launch_bounds__(576, 1) void k_gemm256(
    const USH* __restrict__ xb,
    const USH* __restrict__ wqt, const USH* __restrict__ wkt,
    const float* __restrict__ bq, const float* __restrict__ bk,
    USH* __restrict__ Qb, USH* __restrict__ Kb,
    const USH* __restrict__ wvoT, const float* __restrict__ bvo,
    float* __restrict__ vw) {
  __shared__ USH As[2][16384];
  __shared__ USH Bs[2][16384];
  const int t = threadIdx.x;
  const int w = t >> 6;
  if (w == 8) {
    // vw wave: vw[b][h][s] = xb[row,:] @ wvoT[h,:] + bvo[h]; rows bid*16..+16.
    // Executes EXACTLY the same barrier count as gemm waves: 1 + 32 + 31 = 64.
    const int lane2 = t & 63;
    const int lr2 = lane2 & 15, g2 = lane2 >> 4;
    const int r0 = blockIdx.x * 16;
    v4f acc2 = (v4f){0.f, 0.f, 0.f, 0.f};
    const USH* ap = xb + (size_t)(r0 + lr2) * DD + g2 * 8;
    const USH* bp = wvoT + (size_t)lr2 * DD + g2 * 8;
    __builtin_amdgcn_s_barrier();  // matches prologue barrier
    for (int kt = 0; kt < 32; ++kt) {
      v8bf a0 = *(const v8bf*)(ap + (2 * kt) * 32);
      v8bf b0 = *(const v8bf*)(bp + (2 * kt) * 32);
      acc2 = __builtin_amdgcn_mfma_f32_16x16x32_bf16(a0, b0, acc2, 0, 0, 0);
      v8bf a1 = *(const v8bf*)(ap + (2 * kt + 1) * 32);
      v8bf b1 = *(const v8bf*)(bp + (2 * kt + 1) * 32);
      acc2 = __builtin_amdgcn_mfma_f32_16x16x32_bf16(a1, b1, acc2, 0, 0, 0);
      __builtin_amdgcn_s_barrier();                       // matches barrier B
      if (kt < 31) __builtin_amdgcn_s_barrier();          // matches barrier C
    }
    const float bb = bvo[lr2];
#pragma unroll
    for (int rr = 0; rr < 4; ++rr) {
      const int row = r0 + g2 * 4 + rr;
      vw[((size_t)(row >> 11) * NH + lr2) * SB + (row & 2047)] = acc2[rr] + bb;
    }
    return;
  }
  const int fid = blockIdx.x;
  const int nid = (fid & 7) * 32 + (fid >> 3);
  const int z = nid >> 7;
  const int ty = (nid >> 3) & 15, tx = nid & 7;
  const int row0 = ty * 256, col0 = tx * 256;
  const USH* wt = z ? wkt : wqt;
  const float* bias = z ? bk : bq;
  USH* outp = z ? Kb : Qb;
  const float qscale = z ? 1.0f : 0.08838834764831845f;
  const int lane = t & 63;
  const int lr = lane & 15, g = lane >> 4;
  const int wr = w >> 2, wc = w & 3;
  size_t gA[4], gB[4];
  int ldsOff[4];
#pragma unroll
  for (int q = 0; q < 4; ++q) {
    const int p = q * 512 + t;
    const int row = p >> 3, ps = p & 7;
    const int sl = ps ^ (row & 7);
    gA[q] = (size_t)(row0 + row) * DD + sl * 8;
    gB[q] = (size_t)(col0 + row) * DD + sl * 8;
    ldsOff[q] = p * 8;
  }
  const int swz = (g ^ (lr & 7)) * 8;
  const int k1o = swz ^ 32;
  const int rowA = wr * 128 + lr;
  const int rowB = wc * 64 + lr;

  v4f acc[8][4];
#pragma unroll
  for (int i = 0; i < 8; ++i)
#pragma unroll
    for (int j = 0; j < 4; ++j) acc[i][j] = (v4f){0.f, 0.f, 0.f, 0.f};

#pragma unroll
  for (int q = 0; q < 4; ++q) {
    GL16(xb + gA[q], &As[0][ldsOff[q]]);
    GL16(wt + gB[q], &Bs[0][ldsOff[q]]);
  }
#pragma unroll
  for (int q = 0; q < 4; ++q) {
    GL16(xb + gA[q] + 64, &As[1][ldsOff[q]]);
    GL16(wt + gB[q] + 64, &Bs[1][ldsOff[q]]);
  }
  asm volatile("s_waitcnt vmcnt(8)" ::: "memory");
  __builtin_amdgcn_s_barrier();
  __builtin_amdgcn_sched_barrier(0);

  v8bf bfr0[4], bfr1[4], af0[4], af4[4], af1[4], af5[4];
#pragma unroll
  for (int ni = 0; ni < 4; ++ni)
    bfr0[ni] = *(const v8bf*)&Bs[0][(rowB + ni * 16) * 64 + swz];
#pragma unroll
  for (int mi = 0; mi < 4; ++mi)
    af0[mi] = *(const v8bf*)&As[0][(rowA + mi * 16) * 64 + swz];

  for (int kt = 0; kt < 32; ++kt) {
    const int c = kt & 1;
    const USH* Ab = &As[c][0];
    const USH* Bb = &Bs[c][0];
    // ph0: read af4; wait boundary reads; MFMA q0
    __builtin_amdgcn_sched_barrier(0);
#pragma unroll
    for (int mi = 0; mi < 4; ++mi)
      af4[mi] = *(const v8bf*)&Ab[(rowA + (mi + 4) * 16) * 64 + swz];
    asm volatile("s_waitcnt lgkmcnt(4)" ::: "memory");
    __builtin_amdgcn_sched_barrier(0);
    __builtin_amdgcn_s_setprio(1);
#pragma unroll
    for (int mi = 0; mi < 4; ++mi)
#pragma unroll
      for (int ni = 0; ni < 4; ++ni)
        acc[mi][ni] = __builtin_amdgcn_mfma_f32_16x16x32_bf16(af0[mi], bfr0[ni], acc[mi][ni], 0, 0, 0);
    __builtin_amdgcn_s_setprio(0);
    // ph1: read bfr1, af1; wait af4; MFMA q1
    __builtin_amdgcn_sched_barrier(0);
#pragma unroll
    for (int ni = 0; ni < 4; ++ni)
      bfr1[ni] = *(const v8bf*)&Bb[(rowB + ni * 16) * 64 + k1o];
#pragma unroll
    for (int mi = 0; mi < 4; ++mi)
      af1[mi] = *(const v8bf*)&Ab[(rowA + mi * 16) * 64 + k1o];
    asm volatile("s_waitcnt lgkmcnt(8)" ::: "memory");
    __builtin_amdgcn_sched_barrier(0);
    __builtin_amdgcn_s_setprio(1);
#pragma unroll
    for (int mi = 0; mi < 4; ++mi)
#pragma unroll
      for (int ni = 0; ni < 4; ++ni)
        acc[mi + 4][ni] = __builtin_amdgcn_mfma_f32_16x16x32_bf16(af4[mi], bfr0[ni], acc[mi + 4][ni], 0, 0, 0);
    __builtin_amdgcn_s_setprio(0);
    // ph2: read af5; wait bfr1/af1; MFMA q2
    __builtin_amdgcn_sched_barrier(0);
#pragma unroll
    for (int mi = 0; mi < 4; ++mi)
      af5[mi] = *(const v8bf*)&Ab[(rowA + (mi + 4) * 16) * 64 + k1o];
    asm volatile("s_waitcnt lgkmcnt(4)" ::: "memory");
    __builtin_amdgcn_sched_barrier(0);
    __builtin_amdgcn_s_setprio(1);
#pragma unroll
    for (int mi = 0; mi < 4; ++mi)
#pragma unroll
      for (int ni = 0; ni < 4; ++ni)
        acc[mi][ni] = __builtin_amdgcn_mfma_f32_16x16x32_bf16(af1[mi], bfr1[ni], acc[mi][ni], 0, 0, 0);
    __builtin_amdgcn_s_setprio(0);
    // ph3: drain own reads; barrier B; stage kt+2; MFMA q3
    asm volatile("s_waitcnt lgkmcnt(0)" ::: "memory");
    __builtin_amdgcn_sched_barrier(0);
    __builtin_amdgcn_s_barrier();
    if (kt < 30) {
      const size_t ko = (size_t)(kt + 2) * 64;
#pragma unroll
      for (int q = 0; q < 4; ++q) {
        GL16(xb + gA[q] + ko, &As[c][ldsOff[q]]);
        GL16(wt + gB[q] + ko, &Bs[c][ldsOff[q]]);
      }
    }
    __builtin_amdgcn_s_setprio(1);
#pragma unroll
    for (int mi = 0; mi < 4; ++mi)
#pragma unroll
      for (int ni = 0; ni < 4; ++ni)
        acc[mi + 4][ni] = __builtin_amdgcn_mfma_f32_16x16x32_bf16(af5[mi], bfr1[ni], acc[mi + 4][ni], 0, 0, 0);
    __builtin_amdgcn_s_setprio(0);
    if (kt < 31) {
      if (kt < 30) {
        asm volatile("s_waitcnt vmcnt(8)" ::: "memory");
      } else {
        asm volatile("s_waitcnt vmcnt(0)" ::: "memory");
      }
      __builtin_amdgcn_s_barrier();  // barrier C
      __builtin_amdgcn_sched_barrier(0);
      const USH* An = &As[c ^ 1][0];
      const USH* Bn = &Bs[c ^ 1][0];
#pragma unroll
      for (int ni = 0; ni < 4; ++ni)
        bfr0[ni] = *(const v8bf*)&Bn[(rowB + ni * 16) * 64 + swz];
#pragma unroll
      for (int mi = 0; mi < 4; ++mi)
        af0[mi] = *(const v8bf*)&An[(rowA + mi * 16) * 64 + swz];
    }
  }

  // epilogue: line-coherent order (4 ni stores of each 128B line adjacent)
  {
    const int hh = (col0 + wc * 64) >> 7;
    const int dpb = (wc & 1) * 64;
    float bvv[4];
#pragma unroll
    for (int ni = 0; ni < 4; ++ni)
      bvv[ni] = bias[col0 + wc * 64 + ni * 16 + lr];
#pragma unroll
    for (int mi = 0; mi < 8; ++mi) {
#pragma unroll
      for (int rr = 0; rr < 4; ++rr) {
        const int row = row0 + wr * 128 + mi * 16 + g * 4 + rr;
        const int bi = row >> 11, s = row & 2047;
        USH* op = &outp[(((size_t)bi * NH + hh) * SB + s) * DPH + dpb + lr];
        op[0]  = f2bf((acc[mi][0][rr] + bvv[0]) * qscale);
        op[16] = f2bf((acc[mi][1][rr] + bvv[1]) * qscale);
        op[32] = f2bf((acc[mi][2][rr] + bvv[2]) * qscale);
        op[48] = f2bf((acc[mi][3][rr] + bvv[3]) * qscale);
      }
    }
  }
}

// ---- attention: 8 waves x 16 q-rows; K tiles LDS-staged; NO-MAX softmax;
//      fused final reduce via atomicAdd (out pre-zeroed by k_prep) ----
__global__ __launch_bounds__(512) void k_attn(const USH* __restrict__ Qb,
    const USH* __restrict__ Kb, const float* __restrict__ vw,
    const float* __restrict__ bo, float* __restrict__ out) {
  __shared__ USH Ks[2][8192];
  const int bh = blockIdx.y;
  const int t = threadIdx.x;
  const int wid = t >> 6, lane = t & 63;
  const int lr = lane & 15, g = lane >> 4;
  const int qblk = blockIdx.x * 128;
  const int qb = qblk + wid * 16;
  const USH* Qp = Qb + (size_t)bh * SB * DPH;
  const USH* Kp = Kb + (size_t)bh * SB * DPH;
  const float* vwp = vw + (size_t)bh * SB;

  v8bf qf[4];
  {
    const USH* qrp = Qp + (size_t)(qb + lr) * DPH + g * 8;
#pragma unroll
    for (int kc = 0; kc < 4; ++kc) qf[kc] = *(const v8bf*)(qrp + kc * 32);
  }
  size_t srcO[2];
  int ldsO[2];
#pragma unroll
  for (int q = 0; q < 2; ++q) {
    const int r = t >> 3, ps = t & 7;
    srcO[q] = (size_t)r * DPH + q * 64 + (size_t)(((ps ^ (r & 7)) * 8));
    ldsO[q] = (q * 512 + t) * 8;
  }

  float ls[4], os[4];
#pragma unroll
  for (int r = 0; r < 4; ++r) { ls[r] = 0.f; os[r] = 0.f; }

  const int kb0 = qblk > 511 ? qblk - 512 : 0;
  const int kbend = qblk + 64;

  GL16(Kp + (size_t)kb0 * DPH + srcO[0], &Ks[0][ldsO[0]]);
  GL16(Kp + (size_t)kb0 * DPH + srcO[1], &Ks[0][ldsO[1]]);
  __syncthreads();

  int buf = 0;
  for (int kb = kb0; kb <= kbend; kb += 64, buf ^= 1) {
    if (kb < kbend) {
      GL16(Kp + (size_t)(kb + 64) * DPH + srcO[0], &Ks[buf ^ 1][ldsO[0]]);
      GL16(Kp + (size_t)(kb + 64) * DPH + srcO[1], &Ks[buf ^ 1][ldsO[1]]);
    }
    const USH* base = &Ks[buf][0];
    v4f acc[4];
    float vv[4];
#pragma unroll
    for (int i = 0; i < 4; ++i) {
      v4f a = (v4f){0.f, 0.f, 0.f, 0.f};
#pragma unroll
      for (int kc = 0; kc < 4; ++kc) {
        const int lrow = (kc >> 1) * 64 + i * 16 + lr;
        v8bf kf = *(const v8bf*)&base[lrow * 64 + ((((kc & 1) * 4 + g) ^ (lr & 7)) * 8)];
        a = __builtin_amdgcn_mfma_f32_16x16x32_bf16(qf[kc], kf, a, 0, 0, 0);
      }
      acc[i] = a;
      vv[i] = vwp[kb + i * 16 + lr];
    }
#pragma unroll
    for (int r = 0; r < 4; ++r) {
      const int q_i = qb + g * 4 + r;
      const int k0i = kb + lr;
      float sc0 = acc[0][r], sc1 = acc[1][r], sc2 = acc[2][r], sc3 = acc[3][r];
      sc0 = (k0i <= q_i && q_i - k0i < 512) ? sc0 : -1e30f;
      sc1 = (k0i + 16 <= q_i && q_i - (k0i + 16) < 512) ? sc1 : -1e30f;
      sc2 = (k0i + 32 <= q_i && q_i - (k0i + 32) < 512) ? sc2 : -1e30f;
      sc3 = (k0i + 48 <= q_i && q_i - (k0i + 48) < 512) ? sc3 : -1e30f;
      const float p0 = __expf(sc0);
      const float p1 = __expf(sc1);
      const float p2 = __expf(sc2);
      const float p3 = __expf(sc3);
      ls[r] += (p0 + p1) + (p2 + p3);
      os[r] += (p0 * vv[0] + p1 * vv[1]) + (p2 * vv[2] + p3 * vv[3]);
    }
    __syncthreads();
  }
#pragma unroll
  for (int r = 0; r < 4; ++r) {
    os[r] += __shfl_xor(os[r], 1); ls[r] += __shfl_xor(ls[r], 1);
    os[r] += __shfl_xor(os[r], 2); ls[r] += __shfl_xor(ls[r], 2);
    os[r] += __shfl_xor(os[r], 4); ls[r] += __shfl_xor(ls[r], 4);
    os[r] += __shfl_xor(os[r], 8); ls[r] += __shfl_xor(ls[r], 8);
  }
  if (lr == 0) {
    const float bo16 = bo[0] * 0.0625f;
#pragma unroll
    for (int r = 0; r < 4; ++r)
      atomicAdd(&out[(size_t)(bh >> 4) * SB + qb + g * 4 + r], os[r] / ls[r] + bo16);
  }
}

extern "C" void kernel_launch(void* const* d_in, const int* in_sizes, int n_in,
                              void* d_out, int out_size, void* d_ws, size_t ws_size,
                              hipStream_t stream) {
  const float* x   = (const float*)d_in[0];
  const float* wq  = (const float*)d_in[1];
  const float* bq  = (const float*)d_in[2];
  const float* wk  = (const float*)d_in[3];
  const float* bk  = (const float*)d_in[4];
  const float* wvf = (const float*)d_in[5];
  const float* bvf = (const float*)d_in[6];
  const float* wo  = (const float*)d_in[7];
  const float* bo  = (const float*)d_in[8];
  float* out = (float*)d_out;
  char* ws = (char*)d_ws;

  USH*   wqt = (USH*)(ws);
  USH*   wkt = (USH*)(ws + 8388608);
  USH*   Qb  = (USH*)(ws + 16777216);
  USH*   Kb  = (USH*)(ws + 33554432);
  float* vw  = (float*)(ws + 50331648);
  USH*   wvoT= (USH*)(ws + 50593792);
  float* bvo = (float*)(ws + 50724864);
  USH*   xbf = (USH*)(ws + 50987264);

  k_prep<<<dim3(8194), dim3(256), 0, stream>>>(x, wq, wk, wvf, bvf, wo,
                                               xbf, wqt, wkt, wvoT, bvo, out);
  k_gemm256<<<dim3(256), dim3(576), 0, stream>>>(xbf, wqt, wkt, bq, bk, Qb, Kb,
                                                 wvoT, bvo, vw);
  k_attn<<<dim3(16, 32), dim3(512), 0, stream>>>(Qb, Kb, vw, bo, out);
}

// Round 15
// 116.932 us; speedup vs baseline: 3.5528x; 3.5528x over previous
//
#include <hip/hip_runtime.h>

typedef unsigned short USH;
typedef __bf16 v8bf __attribute__((ext_vector_type(8)));
typedef float v4f __attribute__((ext_vector_type(4)));
typedef unsigned short us8 __attribute__((ext_vector_type(8)));

#define SB 2048
#define DD 2048
#define NH 16
#define DPH 128

__device__ __forceinline__ USH f2bf(float f) {
  unsigned u = __float_as_uint(f);
  u = u + 0x7fffu + ((u >> 16) & 1u);
  return (USH)(u >> 16);
}

#define GL16(gp, lp)                                                   \
  __builtin_amdgcn_global_load_lds(                                    \
      (const __attribute__((address_space(1))) void*)(gp),             \
      (__attribute__((address_space(3))) void*)(lp), 16, 0, 0)

// ---- fused prep: [0,4096) x->bf16 | [4096,6144) transpose wq/wk |
//      [6144,8193) wvo | 8193: zero out ----
__global__ __launch_bounds__(256) void k_prep(const float* __restrict__ x,
    const float* __restrict__ wq, const float* __restrict__ wk,
    const float* __restrict__ wvf, const float* __restrict__ bvf,
    const float* __restrict__ wo,
    USH* __restrict__ xb, USH* __restrict__ wqt, USH* __restrict__ wkt,
    USH* __restrict__ wvoT, float* __restrict__ bvo, float* __restrict__ out) {
  __shared__ USH tl[64][72];
  __shared__ float red[256];
  const int bid = blockIdx.x;
  const int t = threadIdx.x;
  if (bid < 4096) {
    const int i = (bid * 256 + t) * 8;
    const float4 a = *(const float4*)&x[i];
    const float4 b = *(const float4*)&x[i + 4];
    v8bf o;
    o[0] = (__bf16)a.x; o[1] = (__bf16)a.y; o[2] = (__bf16)a.z; o[3] = (__bf16)a.w;
    o[4] = (__bf16)b.x; o[5] = (__bf16)b.y; o[6] = (__bf16)b.z; o[7] = (__bf16)b.w;
    *(v8bf*)&xb[i] = o;
  } else if (bid < 6144) {
    const int rel = bid - 4096;
    const int z = rel >> 10, rem = rel & 1023;
    const float* w = z ? wk : wq;
    USH* wt = z ? wkt : wqt;
    const int k0 = (rem >> 5) * 64, j0 = (rem & 31) * 64;
#pragma unroll
    for (int p = 0; p < 4; ++p) {
      const int r = p * 16 + (t >> 4);
      const int c = (t & 15) * 4;
      const float4 v = *(const float4*)&w[(size_t)(k0 + r) * DD + j0 + c];
      tl[c + 0][r] = f2bf(v.x);
      tl[c + 1][r] = f2bf(v.y);
      tl[c + 2][r] = f2bf(v.z);
      tl[c + 3][r] = f2bf(v.w);
    }
    __syncthreads();
#pragma unroll
    for (int p = 0; p < 2; ++p) {
      const int j = p * 32 + (t >> 3);
      const int seg = (t & 7) * 8;
      us8 v = *(const us8*)&tl[j][seg];
      *(us8*)&wt[(size_t)(j0 + j) * DD + k0 + seg] = v;
    }
  } else if (bid < 8193) {
    const int d = bid - 6144;
    const float* src = (d == DD) ? bvf : (wvf + (size_t)d * DD);
    const float4 a0 = *(const float4*)&src[t * 8];
    const float4 a1 = *(const float4*)&src[t * 8 + 4];
    const float4 w0 = *(const float4*)&wo[t * 8];
    const float4 w1 = *(const float4*)&wo[t * 8 + 4];
    red[t] = a0.x * w0.x + a0.y * w0.y + a0.z * w0.z + a0.w * w0.w +
             a1.x * w1.x + a1.y * w1.y + a1.z * w1.z + a1.w * w1.w;
    __syncthreads();
    for (int s = 8; s > 0; s >>= 1) {
      if ((t & 15) < s) red[t] += red[t + s];
      __syncthreads();
    }
    if ((t & 15) == 0) {
      if (d == DD) bvo[t >> 4] = red[t];
      else wvoT[(size_t)(t >> 4) * DD + d] = f2bf(red[t]);
    }
  } else {
    // zero out[4096] for attn's atomicAdd
#pragma unroll
    for (int i = 0; i < 16; ++i) out[i * 256 + t] = 0.f;
  }
}

// ---- vw[b][h][s] = xb[row,:] @ wvoT[h,:] + bvo[h]; 1 wave x 16 rows per block ----
__global__ __launch_bounds__(64) void k_vw2(const USH* __restrict__ xb,
    const USH* __restrict__ wvoT, const float* __restrict__ bvo,
    float* __restrict__ vw) {
  const int lane = threadIdx.x & 63;
  const int lr = lane & 15, g = lane >> 4;
  const int r0 = blockIdx.x * 16;
  v4f acc = (v4f){0.f, 0.f, 0.f, 0.f};
  const USH* ap = xb + (size_t)(r0 + lr) * DD + g * 8;
  const USH* bp = wvoT + (size_t)lr * DD + g * 8;
#pragma unroll 4
  for (int kt = 0; kt < 64; ++kt) {
    v8bf af = *(const v8bf*)(ap + kt * 32);
    v8bf bf = *(const v8bf*)(bp + kt * 32);
    acc = __builtin_amdgcn_mfma_f32_16x16x32_bf16(af, bf, acc, 0, 0, 0);
  }
  const float bb = bvo[lr];
#pragma unroll
  for (int rr = 0; rr < 4; ++rr) {
    const int row = r0 + g * 4 + rr;
    vw[((size_t)(row >> 11) * NH + lr) * SB + (row & 2047)] = acc[rr] + bb;
  }
}

// ---- 256x256-tile GEMM, BK=64, 8 waves, 2-buf, 4-phase, 2 barriers/tile ----
// R13-proven: 70.4 us, VGPR 128, zero conflicts, zero spill.
__global__ __launch_bounds__(512, 2) void k_gemm256(
    const USH* __restrict__ xb,
    const USH* __restrict__ wqt, const USH* __restrict__ wkt,
    const float* __restrict__ bq, const float* __restrict__ bk,
    USH* __restrict__ Qb, USH* __restrict__ Kb) {
  __shared__ USH As[2][16384];
  __shared__ USH Bs[2][16384];
  const int fid = blockIdx.x;
  const int nid = (fid & 7) * 32 + (fid >> 3);
  const int z = nid >> 7;
  const int ty = (nid >> 3) & 15, tx = nid & 7;
  const int row0 = ty * 256, col0 = tx * 256;
  const USH* wt = z ? wkt : wqt;
  const float* bias = z ? bk : bq;
  USH* outp = z ? Kb : Qb;
  const float qscale = z ? 1.0f : 0.08838834764831845f;
  const int t = threadIdx.x;
  const int w = t >> 6, lane = t & 63;
  const int lr = lane & 15, g = lane >> 4;
  const int wr = w >> 2, wc = w & 3;
  size_t gA[4], gB[4];
  int ldsOff[4];
#pragma unroll
  for (int q = 0; q < 4; ++q) {
    const int p = q * 512 + t;
    const int row = p >> 3, ps = p & 7;
    const int sl = ps ^ (row & 7);
    gA[q] = (size_t)(row0 + row) * DD + sl * 8;
    gB[q] = (size_t)(col0 + row) * DD + sl * 8;
    ldsOff[q] = p * 8;
  }
  const int swz = (g ^ (lr & 7)) * 8;
  const int k1o = swz ^ 32;
  const int rowA = wr * 128 + lr;
  const int rowB = wc * 64 + lr;

  v4f acc[8][4];
#pragma unroll
  for (int i = 0; i < 8; ++i)
#pragma unroll
    for (int j = 0; j < 4; ++j) acc[i][j] = (v4f){0.f, 0.f, 0.f, 0.f};

#pragma unroll
  for (int q = 0; q < 4; ++q) {
    GL16(xb + gA[q], &As[0][ldsOff[q]]);
    GL16(wt + gB[q], &Bs[0][ldsOff[q]]);
  }
#pragma unroll
  for (int q = 0; q < 4; ++q) {
    GL16(xb + gA[q] + 64, &As[1][ldsOff[q]]);
    GL16(wt + gB[q] + 64, &Bs[1][ldsOff[q]]);
  }
  asm volatile("s_waitcnt vmcnt(8)" ::: "memory");
  __builtin_amdgcn_s_barrier();
  __builtin_amdgcn_sched_barrier(0);

  v8bf bfr0[4], bfr1[4], af0[4], af4[4], af1[4], af5[4];
#pragma unroll
  for (int ni = 0; ni < 4; ++ni)
    bfr0[ni] = *(const v8bf*)&Bs[0][(rowB + ni * 16) * 64 + swz];
#pragma unroll
  for (int mi = 0; mi < 4; ++mi)
    af0[mi] = *(const v8bf*)&As[0][(rowA + mi * 16) * 64 + swz];

  for (int kt = 0; kt < 32; ++kt) {
    const int c = kt & 1;
    const USH* Ab = &As[c][0];
    const USH* Bb = &Bs[c][0];
    // ph0: read af4; wait boundary reads; MFMA q0
    __builtin_amdgcn_sched_barrier(0);
#pragma unroll
    for (int mi = 0; mi < 4; ++mi)
      af4[mi] = *(const v8bf*)&Ab[(rowA + (mi + 4) * 16) * 64 + swz];
    asm volatile("s_waitcnt lgkmcnt(4)" ::: "memory");
    __builtin_amdgcn_sched_barrier(0);
    __builtin_amdgcn_s_setprio(1);
#pragma unroll
    for (int mi = 0; mi < 4; ++mi)
#pragma unroll
      for (int ni = 0; ni < 4; ++ni)
        acc[mi][ni] = __builtin_amdgcn_mfma_f32_16x16x32_bf16(af0[mi], bfr0[ni], acc[mi][ni], 0, 0, 0);
    __builtin_amdgcn_s_setprio(0);
    // ph1: read bfr1, af1; wait af4; MFMA q1
    __builtin_amdgcn_sched_barrier(0);
#pragma unroll
    for (int ni = 0; ni < 4; ++ni)
      bfr1[ni] = *(const v8bf*)&Bb[(rowB + ni * 16) * 64 + k1o];
#pragma unroll
    for (int mi = 0; mi < 4; ++mi)
      af1[mi] = *(const v8bf*)&Ab[(rowA + mi * 16) * 64 + k1o];
    asm volatile("s_waitcnt lgkmcnt(8)" ::: "memory");
    __builtin_amdgcn_sched_barrier(0);
    __builtin_amdgcn_s_setprio(1);
#pragma unroll
    for (int mi = 0; mi < 4; ++mi)
#pragma unroll
      for (int ni = 0; ni < 4; ++ni)
        acc[mi + 4][ni] = __builtin_amdgcn_mfma_f32_16x16x32_bf16(af4[mi], bfr0[ni], acc[mi + 4][ni], 0, 0, 0);
    __builtin_amdgcn_s_setprio(0);
    // ph2: read af5; wait bfr1/af1; MFMA q2
    __builtin_amdgcn_sched_barrier(0);
#pragma unroll
    for (int mi = 0; mi < 4; ++mi)
      af5[mi] = *(const v8bf*)&Ab[(rowA + (mi + 4) * 16) * 64 + k1o];
    asm volatile("s_waitcnt lgkmcnt(4)" ::: "memory");
    __builtin_amdgcn_sched_barrier(0);
    __builtin_amdgcn_s_setprio(1);
#pragma unroll
    for (int mi = 0; mi < 4; ++mi)
#pragma unroll
      for (int ni = 0; ni < 4; ++ni)
        acc[mi][ni] = __builtin_amdgcn_mfma_f32_16x16x32_bf16(af1[mi], bfr1[ni], acc[mi][ni], 0, 0, 0);
    __builtin_amdgcn_s_setprio(0);
    // ph3: drain own reads; barrier B; stage kt+2; MFMA q3
    asm volatile("s_waitcnt lgkmcnt(0)" ::: "memory");
    __builtin_amdgcn_sched_barrier(0);
    __builtin_amdgcn_s_barrier();
    if (kt < 30) {
      const size_t ko = (size_t)(kt + 2) * 64;
#pragma unroll
      for (int q = 0; q < 4; ++q) {
        GL16(xb + gA[q] + ko, &As[c][ldsOff[q]]);
        GL16(wt + gB[q] + ko, &Bs[c][ldsOff[q]]);
      }
    }
    __builtin_amdgcn_s_setprio(1);
#pragma unroll
    for (int mi = 0; mi < 4; ++mi)
#pragma unroll
      for (int ni = 0; ni < 4; ++ni)
        acc[mi + 4][ni] = __builtin_amdgcn_mfma_f32_16x16x32_bf16(af5[mi], bfr1[ni], acc[mi + 4][ni], 0, 0, 0);
    __builtin_amdgcn_s_setprio(0);
    if (kt < 31) {
      if (kt < 30) {
        asm volatile("s_waitcnt vmcnt(8)" ::: "memory");
      } else {
        asm volatile("s_waitcnt vmcnt(0)" ::: "memory");
      }
      __builtin_amdgcn_s_barrier();  // barrier C
      __builtin_amdgcn_sched_barrier(0);
      const USH* An = &As[c ^ 1][0];
      const USH* Bn = &Bs[c ^ 1][0];
#pragma unroll
      for (int ni = 0; ni < 4; ++ni)
        bfr0[ni] = *(const v8bf*)&Bn[(rowB + ni * 16) * 64 + swz];
#pragma unroll
      for (int mi = 0; mi < 4; ++mi)
        af0[mi] = *(const v8bf*)&An[(rowA + mi * 16) * 64 + swz];
    }
  }

  // epilogue: line-coherent order (4 ni stores of each 128B line adjacent)
  {
    const int hh = (col0 + wc * 64) >> 7;
    const int dpb = (wc & 1) * 64;
    float bvv[4];
#pragma unroll
    for (int ni = 0; ni < 4; ++ni)
      bvv[ni] = bias[col0 + wc * 64 + ni * 16 + lr];
#pragma unroll
    for (int mi = 0; mi < 8; ++mi) {
#pragma unroll
      for (int rr = 0; rr < 4; ++rr) {
        const int row = row0 + wr * 128 + mi * 16 + g * 4 + rr;
        const int bi = row >> 11, s = row & 2047;
        USH* op = &outp[(((size_t)bi * NH + hh) * SB + s) * DPH + dpb + lr];
        op[0]  = f2bf((acc[mi][0][rr] + bvv[0]) * qscale);
        op[16] = f2bf((acc[mi][1][rr] + bvv[1]) * qscale);
        op[32] = f2bf((acc[mi][2][rr] + bvv[2]) * qscale);
        op[48] = f2bf((acc[mi][3][rr] + bvv[3]) * qscale);
      }
    }
  }
}

// ---- attention: 8 waves x 16 q-rows; K tiles LDS-staged; NO-MAX softmax;
//      fused final reduce via atomicAdd (out pre-zeroed by k_prep) ----
__global__ __launch_bounds__(512) void k_attn(const USH* __restrict__ Qb,
    const USH* __restrict__ Kb, const float* __restrict__ vw,
    const float* __restrict__ bo, float* __restrict__ out) {
  __shared__ USH Ks[2][8192];
  const int bh = blockIdx.y;
  const int t = threadIdx.x;
  const int wid = t >> 6, lane = t & 63;
  const int lr = lane & 15, g = lane >> 4;
  const int qblk = blockIdx.x * 128;
  const int qb = qblk + wid * 16;
  const USH* Qp = Qb + (size_t)bh * SB * DPH;
  const USH* Kp = Kb + (size_t)bh * SB * DPH;
  const float* vwp = vw + (size_t)bh * SB;

  v8bf qf[4];
  {
    const USH* qrp = Qp + (size_t)(qb + lr) * DPH + g * 8;
#pragma unroll
    for (int kc = 0; kc < 4; ++kc) qf[kc] = *(const v8bf*)(qrp + kc * 32);
  }
  size_t srcO[2];
  int ldsO[2];
#pragma unroll
  for (int q = 0; q < 2; ++q) {
    const int r = t >> 3, ps = t & 7;
    srcO[q] = (size_t)r * DPH + q * 64 + (size_t)(((ps ^ (r & 7)) * 8));
    ldsO[q] = (q * 512 + t) * 8;
  }

  float ls[4], os[4];
#pragma unroll
  for (int r = 0; r < 4; ++r) { ls[r] = 0.f; os[r] = 0.f; }

  const int kb0 = qblk > 511 ? qblk - 512 : 0;
  const int kbend = qblk + 64;

  GL16(Kp + (size_t)kb0 * DPH + srcO[0], &Ks[0][ldsO[0]]);
  GL16(Kp + (size_t)kb0 * DPH + srcO[1], &Ks[0][ldsO[1]]);
  __syncthreads();

  int buf = 0;
  for (int kb = kb0; kb <= kbend; kb += 64, buf ^= 1) {
    if (kb < kbend) {
      GL16(Kp + (size_t)(kb + 64) * DPH + srcO[0], &Ks[buf ^ 1][ldsO[0]]);
      GL16(Kp + (size_t)(kb + 64) * DPH + srcO[1], &Ks[buf ^ 1][ldsO[1]]);
    }
    const USH* base = &Ks[buf][0];
    v4f acc[4];
    float vv[4];
#pragma unroll
    for (int i = 0; i < 4; ++i) {
      v4f a = (v4f){0.f, 0.f, 0.f, 0.f};
#pragma unroll
      for (int kc = 0; kc < 4; ++kc) {
        const int lrow = (kc >> 1) * 64 + i * 16 + lr;
        v8bf kf = *(const v8bf*)&base[lrow * 64 + ((((kc & 1) * 4 + g) ^ (lr & 7)) * 8)];
        a = __builtin_amdgcn_mfma_f32_16x16x32_bf16(qf[kc], kf, a, 0, 0, 0);
      }
      acc[i] = a;
      vv[i] = vwp[kb + i * 16 + lr];
    }
#pragma unroll
    for (int r = 0; r < 4; ++r) {
      const int q_i = qb + g * 4 + r;
      const int k0i = kb + lr;
      float sc0 = acc[0][r], sc1 = acc[1][r], sc2 = acc[2][r], sc3 = acc[3][r];
      sc0 = (k0i <= q_i && q_i - k0i < 512) ? sc0 : -1e30f;
      sc1 = (k0i + 16 <= q_i && q_i - (k0i + 16) < 512) ? sc1 : -1e30f;
      sc2 = (k0i + 32 <= q_i && q_i - (k0i + 32) < 512) ? sc2 : -1e30f;
      sc3 = (k0i + 48 <= q_i && q_i - (k0i + 48) < 512) ? sc3 : -1e30f;
      const float p0 = __expf(sc0);
      const float p1 = __expf(sc1);
      const float p2 = __expf(sc2);
      const float p3 = __expf(sc3);
      ls[r] += (p0 + p1) + (p2 + p3);
      os[r] += (p0 * vv[0] + p1 * vv[1]) + (p2 * vv[2] + p3 * vv[3]);
    }
    __syncthreads();
  }
#pragma unroll
  for (int r = 0; r < 4; ++r) {
    os[r] += __shfl_xor(os[r], 1); ls[r] += __shfl_xor(ls[r], 1);
    os[r] += __shfl_xor(os[r], 2); ls[r] += __shfl_xor(ls[r], 2);
    os[r] += __shfl_xor(os[r], 4); ls[r] += __shfl_xor(ls[r], 4);
    os[r] += __shfl_xor(os[r], 8); ls[r] += __shfl_xor(ls[r], 8);
  }
  if (lr == 0) {
    const float bo16 = bo[0] * 0.0625f;
#pragma unroll
    for (int r = 0; r < 4; ++r)
      atomicAdd(&out[(size_t)(bh >> 4) * SB + qb + g * 4 + r], os[r] / ls[r] + bo16);
  }
}

extern "C" void kernel_launch(void* const* d_in, const int* in_sizes, int n_in,
                              void* d_out, int out_size, void* d_ws, size_t ws_size,
                              hipStream_t stream) {
  const float* x   = (const float*)d_in[0];
  const float* wq  = (const float*)d_in[1];
  const float* bq  = (const float*)d_in[2];
  const float* wk  = (const float*)d_in[3];
  const float* bk  = (const float*)d_in[4];
  const float* wvf = (const float*)d_in[5];
  const float* bvf = (const float*)d_in[6];
  const float* wo  = (const float*)d_in[7];
  const float* bo  = (const float*)d_in[8];
  float* out = (float*)d_out;
  char* ws = (char*)d_ws;

  USH*   wqt = (USH*)(ws);
  USH*   wkt = (USH*)(ws + 8388608);
  USH*   Qb  = (USH*)(ws + 16777216);
  USH*   Kb  = (USH*)(ws + 33554432);
  float* vw  = (float*)(ws + 50331648);
  USH*   wvoT= (USH*)(ws + 50593792);
  float* bvo = (float*)(ws + 50724864);
  USH*   xbf = (USH*)(ws + 50987264);

  k_prep<<<dim3(8194), dim3(256), 0, stream>>>(x, wq, wk, wvf, bvf, wo,
                                               xbf, wqt, wkt, wvoT, bvo, out);
  k_vw2<<<dim3(256), dim3(64), 0, stream>>>(xbf, wvoT, bvo, vw);
  k_gemm256<<<dim3(256), dim3(512), 0, stream>>>(xbf, wqt, wkt, bq, bk, Qb, Kb);
  k_attn<<<dim3(16, 32), dim3(512), 0, stream>>>(Qb, Kb, vw, bo, out);
}